// Round 6
// baseline (360.758 us; speedup 1.0000x reference)
//
#include <hip/hip_runtime.h>
#include <hip/hip_bf16.h>

#define T_WORDS 800000
#define S_SENT 2048
#define DIN 256
#define DOUT 128
#define CHUNK 32

typedef short bf16x8 __attribute__((ext_vector_type(8)));
typedef float f32x4 __attribute__((ext_vector_type(4)));

union V16 { bf16x8 v; unsigned int u[4]; };

__device__ __forceinline__ unsigned int pk2(float lo, float hi) {
  // paired _rn cast lowers to v_cvt_pk_bf16_f32 (RNE)
  __hip_bfloat162 h = __float22bfloat162_rn(float2{lo, hi});
  unsigned int u;
  __builtin_memcpy(&u, &h, sizeof(u));
  return u;
}

__device__ __forceinline__ unsigned short f2bf(float f) {
  unsigned int u = __builtin_bit_cast(unsigned int, f);
  u += 0x7fffu + ((u >> 16) & 1u);
  return (unsigned short)(u >> 16);
}

// Prep: weight f32 -> bf16 into ws; sentence start offsets from sorted seg_ids.
__global__ void prep_kernel(const float* __restrict__ weight,
                            const int* __restrict__ seg,
                            unsigned short* __restrict__ wsB,
                            int* __restrict__ starts) {
  int tid = blockIdx.x * blockDim.x + threadIdx.x;
  int stride = gridDim.x * blockDim.x;
  for (int j = tid; j < DOUT * DIN; j += stride)
    wsB[j] = f2bf(weight[j]);
  for (int j = tid; j < T_WORDS; j += stride) {
    if (j == 0) {
      starts[seg[0]] = 0;
    } else {
      int s1 = seg[j], s0 = seg[j - 1];
      if (s1 != s0) starts[s1] = j;
    }
  }
}

// One block per sentence. 4 waves; wave w owns output cols [32w, 32w+32).
// R2 pipeline order: ISSUE(c+1) -> COMPUTE(c) -> WRITE(c+1) -> barrier.
// 4 blocks/CU (128-VGPR cap): 2048 blocks = exactly 2 scheduling rounds.
__global__ __launch_bounds__(256, 4) void pool_kernel(
    const float* __restrict__ tokens,
    const float* __restrict__ bias,
    const unsigned short* __restrict__ wsB,
    const int* __restrict__ starts,
    const int* __restrict__ sent_batch,
    const int* __restrict__ sent_pos,
    float* __restrict__ out) {
  __shared__ alignas(16) unsigned short Alds[2][CHUNK * DIN];  // 2 x 16 KB

  const int s = blockIdx.x;
  const int start = starts[s];
  const int end = (s == S_SENT - 1) ? T_WORDS : starts[s + 1];
  const int lane = (int)(threadIdx.x & 63);
  const int wv = (int)(threadIdx.x >> 6);

  // B fragments: lane holds col = 32*wv + 16n + (lane&15), k = 8*(lane>>4)+j.
  bf16x8 bfrag[2][8];
#pragma unroll
  for (int n = 0; n < 2; ++n) {
    const int col = 32 * wv + 16 * n + (lane & 15);
    const unsigned short* wrow = wsB + col * DIN + 8 * (lane >> 4);
#pragma unroll
    for (int kk = 0; kk < 8; ++kk)
      bfrag[n][kk] = *(const bf16x8*)(wrow + 32 * kk);
  }

  // Staging map: thread t, iter it covers row = (t>>5) + 8*it,
  // f32 cols [8*(t&31), +8) -> 2 float4 loads (32B contiguous per thread).
  const int srow0 = (int)(threadIdx.x >> 5);
  const int sk8 = (int)(threadIdx.x & 31);

  float runmax0 = -INFINITY, runmax1 = -INFINITY;
  float4 pf[4][2];

#define ISSUE(WBASE)                                                          \
  {                                                                           \
    _Pragma("unroll") for (int it = 0; it < 4; ++it) {                        \
      int word = (WBASE) + srow0 + 8 * it;                                    \
      if (word < end) {                                                       \
        const float4* src =                                                   \
            (const float4*)(tokens + (size_t)word * DIN + sk8 * 8);           \
        pf[it][0] = src[0];                                                   \
        pf[it][1] = src[1];                                                   \
      }                                                                       \
    }                                                                         \
  }

  // OOB rows staged as bf16 -inf (0xFF80) so the fold is unconditional.
#define WRITE(WBASE, BUF)                                                     \
  {                                                                           \
    _Pragma("unroll") for (int it = 0; it < 4; ++it) {                        \
      int row = srow0 + 8 * it;                                               \
      bool valid = (WBASE) + row < end;                                       \
      V16 w;                                                                  \
      w.u[0] = valid ? pk2(pf[it][0].x, pf[it][0].y) : 0xFF80FF80u;           \
      w.u[1] = valid ? pk2(pf[it][0].z, pf[it][0].w) : 0xFF80FF80u;           \
      w.u[2] = valid ? pk2(pf[it][1].x, pf[it][1].y) : 0xFF80FF80u;           \
      w.u[3] = valid ? pk2(pf[it][1].z, pf[it][1].w) : 0xFF80FF80u;           \
      int idx = (row * DIN + sk8 * 8) ^ ((row & 7) << 3);                     \
      *(bf16x8*)&Alds[BUF][idx] = w.v;                                        \
    }                                                                         \
  }

#define COMPUTE(BUF)                                                          \
  {                                                                           \
    _Pragma("unroll") for (int m = 0; m < 2; ++m) {                           \
      f32x4 acc0 = (f32x4){0.f, 0.f, 0.f, 0.f};                               \
      f32x4 acc1 = (f32x4){0.f, 0.f, 0.f, 0.f};                               \
      const int arow = 16 * m + (lane & 15);                                  \
      const int abase = arow * DIN + 8 * (lane >> 4);                         \
      const int axor = (lane & 7) << 3;                                       \
      _Pragma("unroll") for (int kk = 0; kk < 8; ++kk) {                      \
        bf16x8 a = *(const bf16x8*)&Alds[BUF][(abase + 32 * kk) ^ axor];      \
        acc0 = __builtin_amdgcn_mfma_f32_16x16x32_bf16(a, bfrag[0][kk], acc0, \
                                                       0, 0, 0);              \
        acc1 = __builtin_amdgcn_mfma_f32_16x16x32_bf16(a, bfrag[1][kk], acc1, \
                                                       0, 0, 0);              \
      }                                                                       \
      runmax0 = fmaxf(runmax0, fmaxf(fmaxf(acc0[0], acc0[1]),                 \
                                     fmaxf(acc0[2], acc0[3])));               \
      runmax1 = fmaxf(runmax1, fmaxf(fmaxf(acc1[0], acc1[1]),                 \
                                     fmaxf(acc1[2], acc1[3])));               \
    }                                                                         \
  }

  // lgkm-only barrier: ds ops drained, global loads (vmcnt) stay in flight.
#define BAR()                                                                 \
  {                                                                           \
    asm volatile("s_waitcnt lgkmcnt(0)" ::: "memory");                        \
    __builtin_amdgcn_s_barrier();                                             \
  }

  const int nch = (end - start + CHUNK - 1) / CHUNK;

  // Prologue: chunk 0 staged into buf0.
  ISSUE(start)
  WRITE(start, 0)
  BAR()

  int c = 0;
  while (true) {
    int wb = start + c * CHUNK;
    // even chunk: issue c+1; compute buf0; stage c+1 -> buf1
    if (c + 1 < nch) ISSUE(wb + CHUNK)
    COMPUTE(0)
    if (c + 1 < nch) WRITE(wb + CHUNK, 1)
    BAR()
    if (++c >= nch) break;

    wb = start + c * CHUNK;
    // odd chunk: issue c+1; compute buf1; stage c+1 -> buf0
    if (c + 1 < nch) ISSUE(wb + CHUNK)
    COMPUTE(1)
    if (c + 1 < nch) WRITE(wb + CHUNK, 0)
    BAR()
    if (++c >= nch) break;
  }

  // Reduce across the 4 row-groups (lanes differing in bits 4,5).
  runmax0 = fmaxf(runmax0, __shfl_xor(runmax0, 16, 64));
  runmax0 = fmaxf(runmax0, __shfl_xor(runmax0, 32, 64));
  runmax1 = fmaxf(runmax1, __shfl_xor(runmax1, 16, 64));
  runmax1 = fmaxf(runmax1, __shfl_xor(runmax1, 32, 64));

  if (lane < 16) {
    const int sb = sent_batch[s], sp = sent_pos[s];
    float* o = out + ((size_t)sb * 64 + sp) * DOUT;
    const int c0 = 32 * wv + lane;
    o[c0] = runmax0 + bias[c0];
    o[c0 + 16] = runmax1 + bias[c0 + 16];
  }
}

extern "C" void kernel_launch(void* const* d_in, const int* in_sizes, int n_in,
                              void* d_out, int out_size, void* d_ws, size_t ws_size,
                              hipStream_t stream) {
  const float* tokens = (const float*)d_in[0];
  const float* weight = (const float*)d_in[1];
  const float* bias   = (const float*)d_in[2];
  const int* seg      = (const int*)d_in[3];
  const int* sbatch   = (const int*)d_in[4];
  const int* spos     = (const int*)d_in[5];
  float* out = (float*)d_out;

  unsigned short* wsB = (unsigned short*)d_ws;                    // 64 KB bf16 weight
  int* starts = (int*)((char*)d_ws + DOUT * DIN * sizeof(unsigned short));  // 8 KB

  prep_kernel<<<512, 256, 0, stream>>>(weight, seg, wsB, starts);
  pool_kernel<<<S_SENT, 256, 0, stream>>>(tokens, bias, wsB, starts, sbatch, spos, out);
}

// Round 7
// 344.296 us; speedup vs baseline: 1.0478x; 1.0478x over previous
//
#include <hip/hip_runtime.h>
#include <hip/hip_bf16.h>

#define T_WORDS 800000
#define S_SENT 2048
#define DIN 256
#define DOUT 128
#define CHUNK 32
#define TILES 25000        // T_WORDS / CHUNK, exact
#define GRID_P 768         // 256 CU x 3 blocks/CU
#define OUT_ELEMS (32 * 64 * DOUT)

typedef short bf16x8 __attribute__((ext_vector_type(8)));
typedef float f32x4 __attribute__((ext_vector_type(4)));

union V16 { bf16x8 v; unsigned int u[4]; };

__device__ __forceinline__ unsigned int pk2(float lo, float hi) {
  __hip_bfloat162 h = __float22bfloat162_rn(float2{lo, hi});
  unsigned int u;
  __builtin_memcpy(&u, &h, sizeof(u));
  return u;
}

__device__ __forceinline__ unsigned short f2bf(float f) {
  unsigned int u = __builtin_bit_cast(unsigned int, f);
  u += 0x7fffu + ((u >> 16) & 1u);
  return (unsigned short)(u >> 16);
}

// Order-preserving f32 -> u32 key: f1 > f2  <=>  key(f1) > key(f2) (unsigned).
__device__ __forceinline__ unsigned int fkey(float f) {
  unsigned int u = __builtin_bit_cast(unsigned int, f);
  return (u & 0x80000000u) ? ~u : (u | 0x80000000u);
}

// Prep: weight->bf16; starts[] from sorted seg_ids (+ sentinel); out keys = -inf.
__global__ void prep_kernel(const float* __restrict__ weight,
                            const int* __restrict__ seg,
                            unsigned short* __restrict__ wsB,
                            int* __restrict__ starts,
                            unsigned int* __restrict__ outk) {
  int tid = blockIdx.x * blockDim.x + threadIdx.x;
  int stride = gridDim.x * blockDim.x;
  for (int j = tid; j < DOUT * DIN; j += stride)
    wsB[j] = f2bf(weight[j]);
  for (int j = tid; j < OUT_ELEMS; j += stride)
    outk[j] = 0x007FFFFFu;                     // key(-inf)
  for (int j = tid; j < T_WORDS; j += stride) {
    if (j == 0) {
      starts[seg[0]] = 0;
      starts[S_SENT] = T_WORDS;                // sentinel
    } else {
      int s1 = seg[j], s0 = seg[j - 1];
      if (s1 != s0) starts[s1] = j;
    }
  }
}

// 768 blocks; block b owns a contiguous tile-aligned word range (~1042 words).
// R2 pipeline per 32-row chunk; segment-boundary-aware fold with atomic flush.
__global__ __launch_bounds__(256, 3) void pool_kernel(
    const float* __restrict__ tokens,
    const unsigned short* __restrict__ wsB,
    const int* __restrict__ starts,
    const int* __restrict__ seg_ids,
    const int* __restrict__ sent_batch,
    const int* __restrict__ sent_pos,
    unsigned int* __restrict__ outk) {
  __shared__ alignas(16) unsigned short Alds[2][CHUNK * DIN];  // 2 x 16 KB

  const int b = blockIdx.x;
  const int t0 = (int)(((long long)b * TILES) / GRID_P);
  const int t1 = (int)(((long long)(b + 1) * TILES) / GRID_P);
  const int w_begin = t0 * CHUNK;
  const int nch = t1 - t0;                     // 32 or 33

  const int lane = (int)(threadIdx.x & 63);
  const int wv = (int)(threadIdx.x >> 6);

  // B fragments: lane holds col = 32*wv + 16n + (lane&15), k = 8*(lane>>4)+j.
  bf16x8 bfrag[2][8];
#pragma unroll
  for (int n = 0; n < 2; ++n) {
    const int col = 32 * wv + 16 * n + (lane & 15);
    const unsigned short* wrow = wsB + col * DIN + 8 * (lane >> 4);
#pragma unroll
    for (int kk = 0; kk < 8; ++kk)
      bfrag[n][kk] = *(const bf16x8*)(wrow + 32 * kk);
  }

  // Staging map: thread t, iter it covers row = (t>>5) + 8*it, f32 cols [8*(t&31), +8).
  const int srow0 = (int)(threadIdx.x >> 5);
  const int sk8 = (int)(threadIdx.x & 31);

  float runmax0 = -INFINITY, runmax1 = -INFINITY;
  float4 pf[4][2];
  f32x4 acc0[2], acc1[2];

  int cur = seg_ids[w_begin];                  // segment of first row
  int hi = starts[cur + 1];                    // its end (exclusive)

#define ISSUE(WBASE)                                                          \
  {                                                                           \
    _Pragma("unroll") for (int it = 0; it < 4; ++it) {                        \
      const float4* src = (const float4*)(tokens +                            \
          (size_t)((WBASE) + srow0 + 8 * it) * DIN + sk8 * 8);                \
      pf[it][0] = src[0];                                                     \
      pf[it][1] = src[1];                                                     \
    }                                                                         \
  }

#define WRITE(BUFP)                                                           \
  {                                                                           \
    _Pragma("unroll") for (int it = 0; it < 4; ++it) {                        \
      int row = srow0 + 8 * it;                                               \
      V16 w;                                                                  \
      w.u[0] = pk2(pf[it][0].x, pf[it][0].y);                                 \
      w.u[1] = pk2(pf[it][0].z, pf[it][0].w);                                 \
      w.u[2] = pk2(pf[it][1].x, pf[it][1].y);                                 \
      w.u[3] = pk2(pf[it][1].z, pf[it][1].w);                                 \
      int idx = (row * DIN + sk8 * 8) ^ ((row & 7) << 3);                     \
      *(bf16x8*)&(BUFP)[idx] = w.v;                                           \
    }                                                                         \
  }

#define COMPUTE(BUFP)                                                         \
  {                                                                           \
    _Pragma("unroll") for (int m = 0; m < 2; ++m) {                           \
      acc0[m] = (f32x4){0.f, 0.f, 0.f, 0.f};                                  \
      acc1[m] = (f32x4){0.f, 0.f, 0.f, 0.f};                                  \
      const int arow = 16 * m + (lane & 15);                                  \
      const int abase = arow * DIN + 8 * (lane >> 4);                         \
      const int axor = (lane & 7) << 3;                                       \
      _Pragma("unroll") for (int kk = 0; kk < 8; ++kk) {                      \
        bf16x8 a = *(const bf16x8*)&(BUFP)[(abase + 32 * kk) ^ axor];         \
        acc0[m] = __builtin_amdgcn_mfma_f32_16x16x32_bf16(a, bfrag[0][kk],    \
                                                          acc0[m], 0, 0, 0); \
        acc1[m] = __builtin_amdgcn_mfma_f32_16x16x32_bf16(a, bfrag[1][kk],    \
                                                          acc1[m], 0, 0, 0); \
      }                                                                       \
    }                                                                         \
  }

#define FLUSH(SEG)                                                            \
  {                                                                           \
    float f0 = fmaxf(runmax0, __shfl_xor(runmax0, 16, 64));                   \
    f0 = fmaxf(f0, __shfl_xor(f0, 32, 64));                                   \
    float f1 = fmaxf(runmax1, __shfl_xor(runmax1, 16, 64));                   \
    f1 = fmaxf(f1, __shfl_xor(f1, 32, 64));                                   \
    if (lane < 16) {                                                          \
      int oi = (sent_batch[SEG] * 64 + sent_pos[SEG]) * DOUT + 32 * wv + lane;\
      atomicMax(&outk[oi], fkey(f0));                                         \
      atomicMax(&outk[oi + 16], fkey(f1));                                    \
    }                                                                         \
  }

#define BAR()                                                                 \
  {                                                                           \
    asm volatile("s_waitcnt lgkmcnt(0)" ::: "memory");                        \
    __builtin_amdgcn_s_barrier();                                             \
  }

  // Prologue: chunk 0 -> buf0.
  ISSUE(w_begin)
  WRITE(Alds[0])
  BAR()

  for (int c = 0; c < nch; ++c) {
    const int wb = w_begin + c * CHUNK;
    unsigned short* curb = Alds[c & 1];
    unsigned short* nxtb = Alds[(c & 1) ^ 1];

    if (c + 1 < nch) ISSUE(wb + CHUNK)
    COMPUTE(curb)

    // Segment-boundary-aware fold of acc into runmax.
    {
      const int wend = wb + CHUNK;
      int flo = wb;
      while (true) {
        const bool full = (hi >= wend);
        const int fhi = full ? wend : hi;
        if (flo == wb && full) {
          // fast path: whole chunk inside cur segment
#pragma unroll
          for (int m = 0; m < 2; ++m) {
            runmax0 = fmaxf(runmax0, fmaxf(fmaxf(acc0[m][0], acc0[m][1]),
                                           fmaxf(acc0[m][2], acc0[m][3])));
            runmax1 = fmaxf(runmax1, fmaxf(fmaxf(acc1[m][0], acc1[m][1]),
                                           fmaxf(acc1[m][2], acc1[m][3])));
          }
        } else {
          const int rb = 4 * (lane >> 4);
#pragma unroll
          for (int m = 0; m < 2; ++m) {
            const int row0 = wb + 16 * m + rb;
#pragma unroll
            for (int r = 0; r < 4; ++r) {
              const bool in = (row0 + r >= flo) && (row0 + r < fhi);
              runmax0 = fmaxf(runmax0, in ? acc0[m][r] : -INFINITY);
              runmax1 = fmaxf(runmax1, in ? acc1[m][r] : -INFINITY);
            }
          }
        }
        if (full) break;
        FLUSH(cur)
        runmax0 = -INFINITY;
        runmax1 = -INFINITY;
        ++cur;
        flo = fhi;
        hi = starts[cur + 1];
      }
    }

    if (c + 1 < nch) WRITE(nxtb)
    BAR()
  }

  // Final flush of the (possibly partial) last segment.
  FLUSH(cur)
}

// Un-key and add bias, in place on d_out.
__global__ void final_kernel(unsigned int* __restrict__ outk,
                             const float* __restrict__ bias) {
  int i = blockIdx.x * blockDim.x + threadIdx.x;
  if (i < OUT_ELEMS) {
    unsigned int k = outk[i];
    unsigned int u = (k & 0x80000000u) ? (k ^ 0x80000000u) : ~k;
    float f = __builtin_bit_cast(float, u);
    ((float*)outk)[i] = f + bias[i & (DOUT - 1)];
  }
}

extern "C" void kernel_launch(void* const* d_in, const int* in_sizes, int n_in,
                              void* d_out, int out_size, void* d_ws, size_t ws_size,
                              hipStream_t stream) {
  const float* tokens = (const float*)d_in[0];
  const float* weight = (const float*)d_in[1];
  const float* bias   = (const float*)d_in[2];
  const int* seg      = (const int*)d_in[3];
  const int* sbatch   = (const int*)d_in[4];
  const int* spos     = (const int*)d_in[5];
  unsigned int* outk = (unsigned int*)d_out;

  unsigned short* wsB = (unsigned short*)d_ws;                       // 64 KB
  int* starts = (int*)((char*)d_ws + DOUT * DIN * sizeof(unsigned short));  // 8.2 KB (S+1)

  prep_kernel<<<512, 256, 0, stream>>>(weight, seg, wsB, starts, outk);
  pool_kernel<<<GRID_P, 256, 0, stream>>>(tokens, wsB, starts, seg, sbatch, spos, outk);
  final_kernel<<<(OUT_ELEMS + 255) / 256, 256, 0, stream>>>(outk, bias);
}

// Round 8
// 163.508 us; speedup vs baseline: 2.2064x; 2.1057x over previous
//
#include <hip/hip_runtime.h>
#include <hip/hip_bf16.h>

#define T_WORDS 800000
#define S_SENT 2048
#define DIN 256
#define DOUT 128
#define CHUNK 32
#define GRID_P 768         // 256 CU x 3 blocks/CU — exact one-round-multiple fit

typedef short bf16x8 __attribute__((ext_vector_type(8)));
typedef float f32x4 __attribute__((ext_vector_type(4)));

union V16 { bf16x8 v; unsigned int u[4]; };

__device__ __forceinline__ unsigned int pk2(float lo, float hi) {
  // paired _rn cast lowers to v_cvt_pk_bf16_f32 (RNE)
  __hip_bfloat162 h = __float22bfloat162_rn(float2{lo, hi});
  unsigned int u;
  __builtin_memcpy(&u, &h, sizeof(u));
  return u;
}

__device__ __forceinline__ unsigned short f2bf(float f) {
  unsigned int u = __builtin_bit_cast(unsigned int, f);
  u += 0x7fffu + ((u >> 16) & 1u);
  return (unsigned short)(u >> 16);
}

// Prep: weight f32 -> bf16; starts[] from sorted seg_ids (+ sentinel).
__global__ void prep_kernel(const float* __restrict__ weight,
                            const int* __restrict__ seg,
                            unsigned short* __restrict__ wsB,
                            int* __restrict__ starts) {
  int tid = blockIdx.x * blockDim.x + threadIdx.x;
  int stride = gridDim.x * blockDim.x;
  for (int j = tid; j < DOUT * DIN; j += stride)
    wsB[j] = f2bf(weight[j]);
  for (int j = tid; j < T_WORDS; j += stride) {
    if (j == 0) {
      starts[seg[0]] = 0;
      starts[S_SENT] = T_WORDS;                // sentinel
    } else {
      int s1 = seg[j], s0 = seg[j - 1];
      if (s1 != s0) starts[s1] = j;
    }
  }
}

__device__ __forceinline__ int lbound(const int* __restrict__ a, int n, int v) {
  int lo = 0, hi = n;
  while (lo < hi) {
    int m = (lo + hi) >> 1;
    if (a[m] < v) lo = m + 1; else hi = m;
  }
  return lo;
}

// 768 blocks; block b owns the sentences whose start offset falls in
// [b*T/P, (b+1)*T/P) — contiguous, ~2.7 sentences (~1042 words) per block.
// Per sentence: the R2 pipeline (ISSUE(c+1) -> COMPUTE(c)+fold -> WRITE(c+1)
// -> lgkm-barrier), -inf staging of ragged tail rows, direct stores.
__global__ __launch_bounds__(256, 3) void pool_kernel(
    const float* __restrict__ tokens,
    const float* __restrict__ bias,
    const unsigned short* __restrict__ wsB,
    const int* __restrict__ starts,
    const int* __restrict__ sent_batch,
    const int* __restrict__ sent_pos,
    float* __restrict__ out) {
  __shared__ alignas(16) unsigned short Alds[2][CHUNK * DIN];  // 2 x 16 KB

  const int b = blockIdx.x;
  // Sentence range [slo, shi): assign(s) = starts[s]*P/T == b.
  const int tgt0 = (int)(((long long)b * T_WORDS + GRID_P - 1) / GRID_P);
  const int tgt1 = (int)(((long long)(b + 1) * T_WORDS + GRID_P - 1) / GRID_P);
  const int slo = lbound(starts, S_SENT, tgt0);
  const int shi = lbound(starts, S_SENT, tgt1);

  const int lane = (int)(threadIdx.x & 63);
  const int wv = (int)(threadIdx.x >> 6);

  // B fragments: lane holds col = 32*wv + 16n + (lane&15), k = 8*(lane>>4)+j.
  bf16x8 bfrag[2][8];
#pragma unroll
  for (int n = 0; n < 2; ++n) {
    const int col = 32 * wv + 16 * n + (lane & 15);
    const unsigned short* wrow = wsB + col * DIN + 8 * (lane >> 4);
#pragma unroll
    for (int kk = 0; kk < 8; ++kk)
      bfrag[n][kk] = *(const bf16x8*)(wrow + 32 * kk);
  }

  // Staging map: thread t, iter it covers row = (t>>5) + 8*it,
  // f32 cols [8*(t&31), +8) -> 2 float4 loads (32B contiguous per thread).
  const int srow0 = (int)(threadIdx.x >> 5);
  const int sk8 = (int)(threadIdx.x & 31);

  float4 pf[4][2];

#define ISSUE(WBASE, END)                                                     \
  {                                                                           \
    _Pragma("unroll") for (int it = 0; it < 4; ++it) {                        \
      int word = (WBASE) + srow0 + 8 * it;                                    \
      if (word < (END)) {                                                     \
        const float4* src =                                                   \
            (const float4*)(tokens + (size_t)word * DIN + sk8 * 8);           \
        pf[it][0] = src[0];                                                   \
        pf[it][1] = src[1];                                                   \
      }                                                                       \
    }                                                                         \
  }

  // OOB rows staged as bf16 -inf (0xFF80) so the fold is unconditional.
#define WRITE(WBASE, END, BUF)                                                \
  {                                                                           \
    _Pragma("unroll") for (int it = 0; it < 4; ++it) {                        \
      int row = srow0 + 8 * it;                                               \
      bool valid = (WBASE) + row < (END);                                     \
      V16 w;                                                                  \
      w.u[0] = valid ? pk2(pf[it][0].x, pf[it][0].y) : 0xFF80FF80u;           \
      w.u[1] = valid ? pk2(pf[it][0].z, pf[it][0].w) : 0xFF80FF80u;           \
      w.u[2] = valid ? pk2(pf[it][1].x, pf[it][1].y) : 0xFF80FF80u;           \
      w.u[3] = valid ? pk2(pf[it][1].z, pf[it][1].w) : 0xFF80FF80u;           \
      int idx = (row * DIN + sk8 * 8) ^ ((row & 7) << 3);                     \
      *(bf16x8*)&Alds[BUF][idx] = w.v;                                        \
    }                                                                         \
  }

#define COMPUTE(BUF)                                                          \
  {                                                                           \
    _Pragma("unroll") for (int m = 0; m < 2; ++m) {                           \
      f32x4 acc0 = (f32x4){0.f, 0.f, 0.f, 0.f};                               \
      f32x4 acc1 = (f32x4){0.f, 0.f, 0.f, 0.f};                               \
      const int arow = 16 * m + (lane & 15);                                  \
      const int abase = arow * DIN + 8 * (lane >> 4);                         \
      const int axor = (lane & 7) << 3;                                       \
      _Pragma("unroll") for (int kk = 0; kk < 8; ++kk) {                      \
        bf16x8 a = *(const bf16x8*)&Alds[BUF][(abase + 32 * kk) ^ axor];      \
        acc0 = __builtin_amdgcn_mfma_f32_16x16x32_bf16(a, bfrag[0][kk], acc0, \
                                                       0, 0, 0);              \
        acc1 = __builtin_amdgcn_mfma_f32_16x16x32_bf16(a, bfrag[1][kk], acc1, \
                                                       0, 0, 0);              \
      }                                                                       \
      runmax0 = fmaxf(runmax0, fmaxf(fmaxf(acc0[0], acc0[1]),                 \
                                     fmaxf(acc0[2], acc0[3])));               \
      runmax1 = fmaxf(runmax1, fmaxf(fmaxf(acc1[0], acc1[1]),                 \
                                     fmaxf(acc1[2], acc1[3])));               \
    }                                                                         \
  }

  // lgkm-only barrier: ds ops drained, global loads (vmcnt) stay in flight.
#define BAR()                                                                 \
  {                                                                           \
    asm volatile("s_waitcnt lgkmcnt(0)" ::: "memory");                        \
    __builtin_amdgcn_s_barrier();                                             \
  }

  for (int s = slo; s < shi; ++s) {
    const int start = starts[s];
    const int end = starts[s + 1];
    const int nch = (end - start + CHUNK - 1) / CHUNK;

    float runmax0 = -INFINITY, runmax1 = -INFINITY;

    // Prologue: chunk 0 staged into buf0.
    ISSUE(start, end)
    WRITE(start, end, 0)
    BAR()

    int c = 0;
    while (true) {
      int wb = start + c * CHUNK;
      // even chunk: issue c+1; compute buf0 (+fold); stage c+1 -> buf1
      if (c + 1 < nch) ISSUE(wb + CHUNK, end)
      COMPUTE(0)
      if (c + 1 < nch) WRITE(wb + CHUNK, end, 1)
      BAR()
      if (++c >= nch) break;

      wb = start + c * CHUNK;
      // odd chunk: issue c+1; compute buf1 (+fold); stage c+1 -> buf0
      if (c + 1 < nch) ISSUE(wb + CHUNK, end)
      COMPUTE(1)
      if (c + 1 < nch) WRITE(wb + CHUNK, end, 0)
      BAR()
      if (++c >= nch) break;
    }

    // Reduce across the 4 row-groups (lanes differing in bits 4,5).
    runmax0 = fmaxf(runmax0, __shfl_xor(runmax0, 16, 64));
    runmax0 = fmaxf(runmax0, __shfl_xor(runmax0, 32, 64));
    runmax1 = fmaxf(runmax1, __shfl_xor(runmax1, 16, 64));
    runmax1 = fmaxf(runmax1, __shfl_xor(runmax1, 32, 64));

    if (lane < 16) {
      const int sb = sent_batch[s], sp = sent_pos[s];
      float* o = out + ((size_t)sb * 64 + sp) * DOUT;
      const int c0 = 32 * wv + lane;
      o[c0] = runmax0 + bias[c0];
      o[c0 + 16] = runmax1 + bias[c0 + 16];
    }
  }
}

extern "C" void kernel_launch(void* const* d_in, const int* in_sizes, int n_in,
                              void* d_out, int out_size, void* d_ws, size_t ws_size,
                              hipStream_t stream) {
  const float* tokens = (const float*)d_in[0];
  const float* weight = (const float*)d_in[1];
  const float* bias   = (const float*)d_in[2];
  const int* seg      = (const int*)d_in[3];
  const int* sbatch   = (const int*)d_in[4];
  const int* spos     = (const int*)d_in[5];
  float* out = (float*)d_out;

  unsigned short* wsB = (unsigned short*)d_ws;                    // 64 KB bf16 weight
  int* starts = (int*)((char*)d_ws + DOUT * DIN * sizeof(unsigned short));  // 8.2 KB (S+1)

  prep_kernel<<<512, 256, 0, stream>>>(weight, seg, wsB, starts);
  pool_kernel<<<GRID_P, 256, 0, stream>>>(tokens, bias, wsB, starts, sbatch, spos, out);
}

// Round 9
// 156.320 us; speedup vs baseline: 2.3078x; 1.0460x over previous
//
#include <hip/hip_runtime.h>
#include <hip/hip_bf16.h>

#define T_WORDS 800000
#define S_SENT 2048
#define DIN 256
#define DOUT 128
#define CHUNK 16

typedef short bf16x8 __attribute__((ext_vector_type(8)));
typedef float f32x4 __attribute__((ext_vector_type(4)));

__device__ __forceinline__ unsigned short f2bf(float f) {
  unsigned int u = __builtin_bit_cast(unsigned int, f);
  u += 0x7fffu + ((u >> 16) & 1u);   // round-to-nearest-even
  return (unsigned short)(u >> 16);
}

// Prep: weight f32 -> bf16 into ws; sentence start offsets from sorted seg_ids.
__global__ void prep_kernel(const float* __restrict__ weight,
                            const int* __restrict__ seg,
                            unsigned short* __restrict__ wsB,
                            int* __restrict__ starts) {
  int tid = blockIdx.x * blockDim.x + threadIdx.x;
  int stride = gridDim.x * blockDim.x;
  for (int j = tid; j < DOUT * DIN; j += stride)
    wsB[j] = f2bf(weight[j]);
  for (int j = tid; j < T_WORDS; j += stride) {
    if (j == 0) {
      starts[seg[0]] = 0;
    } else {
      int s1 = seg[j], s0 = seg[j - 1];
      if (s1 != s0) starts[s1] = j;
    }
  }
}

// One block per sentence. 4 waves; wave w owns output cols [32w, 32w+32).
// R2 structure verbatim, CHUNK=16: register demand ~108 fits the 128 cap,
// so (256,4) -> 4 blocks/CU -> 1024 concurrent -> 2048 blocks = exactly
// 2 scheduling rounds (vs R2's 2.67 -> 3 rounds at 89% packing).
__global__ __launch_bounds__(256, 4) void pool_kernel(
    const float* __restrict__ tokens,
    const float* __restrict__ bias,
    const unsigned short* __restrict__ wsB,
    const int* __restrict__ starts,
    const int* __restrict__ sent_batch,
    const int* __restrict__ sent_pos,
    float* __restrict__ out) {
  __shared__ alignas(16) unsigned short Alds[2][CHUNK * DIN];  // 2 x 8 KB

  const int s = blockIdx.x;
  const int start = starts[s];
  const int end = (s == S_SENT - 1) ? T_WORDS : starts[s + 1];
  const int lane = (int)(threadIdx.x & 63);
  const int wv = (int)(threadIdx.x >> 6);

  // B fragments: lane holds col = 32*wv + 16n + (lane&15), k = 8*(lane>>4)+j.
  bf16x8 bfrag[2][8];
#pragma unroll
  for (int n = 0; n < 2; ++n) {
    const int col = 32 * wv + 16 * n + (lane & 15);
    const unsigned short* wrow = wsB + col * DIN + 8 * (lane >> 4);
#pragma unroll
    for (int kk = 0; kk < 8; ++kk)
      bfrag[n][kk] = *(const bf16x8*)(wrow + 32 * kk);
  }

  // Staging map: g = tid + 256*it (it<2); row = g>>5 (0..15), k8 = g&31;
  // each (row,k8) covers f32 cols [8*k8, 8*k8+8) -> 2 float4 loads.
  const int srow0 = (int)(threadIdx.x >> 5);
  const int sk8 = (int)(threadIdx.x & 31);

  float runmax0 = -INFINITY, runmax1 = -INFINITY;
  float4 pf[2][2];

#define ISSUE(WBASE)                                                          \
  {                                                                           \
    _Pragma("unroll") for (int it = 0; it < 2; ++it) {                        \
      int word = (WBASE) + srow0 + 8 * it;                                    \
      if (word < end) {                                                       \
        const float4* src =                                                   \
            (const float4*)(tokens + (size_t)word * DIN + sk8 * 8);           \
        pf[it][0] = src[0];                                                   \
        pf[it][1] = src[1];                                                   \
      }                                                                       \
    }                                                                         \
  }

#define WRITE(WBASE, BUF)                                                     \
  {                                                                           \
    _Pragma("unroll") for (int it = 0; it < 2; ++it) {                        \
      int row = srow0 + 8 * it;                                               \
      int word = (WBASE) + row;                                               \
      if (word < end) {                                                       \
        float4 f0 = pf[it][0], f1 = pf[it][1];                                \
        bf16x8 v;                                                             \
        v[0] = (short)f2bf(f0.x); v[1] = (short)f2bf(f0.y);                   \
        v[2] = (short)f2bf(f0.z); v[3] = (short)f2bf(f0.w);                   \
        v[4] = (short)f2bf(f1.x); v[5] = (short)f2bf(f1.y);                   \
        v[6] = (short)f2bf(f1.z); v[7] = (short)f2bf(f1.w);                   \
        int idx = (row * DIN + sk8 * 8) ^ ((row & 7) << 3);                   \
        *(bf16x8*)&Alds[BUF][idx] = v;                                        \
      }                                                                       \
    }                                                                         \
  }

#define COMPUTE(BUF, WBASE)                                                   \
  {                                                                           \
    f32x4 acc0 = (f32x4){0.f, 0.f, 0.f, 0.f};                                 \
    f32x4 acc1 = (f32x4){0.f, 0.f, 0.f, 0.f};                                 \
    const int arow = (lane & 15);                                             \
    const int abase = arow * DIN + 8 * (lane >> 4);                           \
    const int axor = (lane & 7) << 3;                                         \
    _Pragma("unroll") for (int kk = 0; kk < 8; ++kk) {                        \
      bf16x8 a = *(const bf16x8*)&Alds[BUF][(abase + 32 * kk) ^ axor];        \
      acc0 = __builtin_amdgcn_mfma_f32_16x16x32_bf16(a, bfrag[0][kk], acc0,   \
                                                     0, 0, 0);                \
      acc1 = __builtin_amdgcn_mfma_f32_16x16x32_bf16(a, bfrag[1][kk], acc1,   \
                                                     0, 0, 0);                \
    }                                                                         \
    const int w0 = (WBASE) + 4 * (lane >> 4);                                 \
    _Pragma("unroll") for (int r = 0; r < 4; ++r) {                           \
      if (w0 + r < end) {                                                     \
        runmax0 = fmaxf(runmax0, acc0[r]);                                    \
        runmax1 = fmaxf(runmax1, acc1[r]);                                    \
      }                                                                       \
    }                                                                         \
  }

  const int nch = (end - start + CHUNK - 1) / CHUNK;

  // Prologue: chunk 0 staged into buf0.
  ISSUE(start)
  WRITE(start, 0)
  __syncthreads();

  int c = 0;
  while (true) {
    int wb = start + c * CHUNK;
    // even chunk: issue c+1; compute buf0; stage c+1 -> buf1
    if (c + 1 < nch) ISSUE(wb + CHUNK)
    COMPUTE(0, wb)
    if (c + 1 < nch) WRITE(wb + CHUNK, 1)
    __syncthreads();
    if (++c >= nch) break;

    wb = start + c * CHUNK;
    // odd chunk: issue c+1; compute buf1; stage c+1 -> buf0
    if (c + 1 < nch) ISSUE(wb + CHUNK)
    COMPUTE(1, wb)
    if (c + 1 < nch) WRITE(wb + CHUNK, 0)
    __syncthreads();
    if (++c >= nch) break;
  }

  // Reduce across the 4 row-groups (lanes differing in bits 4,5).
  runmax0 = fmaxf(runmax0, __shfl_xor(runmax0, 16, 64));
  runmax0 = fmaxf(runmax0, __shfl_xor(runmax0, 32, 64));
  runmax1 = fmaxf(runmax1, __shfl_xor(runmax1, 16, 64));
  runmax1 = fmaxf(runmax1, __shfl_xor(runmax1, 32, 64));

  if (lane < 16) {
    const int sb = sent_batch[s], sp = sent_pos[s];
    float* o = out + ((size_t)sb * 64 + sp) * DOUT;
    const int c0 = 32 * wv + lane;
    o[c0] = runmax0 + bias[c0];
    o[c0 + 16] = runmax1 + bias[c0 + 16];
  }
}

extern "C" void kernel_launch(void* const* d_in, const int* in_sizes, int n_in,
                              void* d_out, int out_size, void* d_ws, size_t ws_size,
                              hipStream_t stream) {
  const float* tokens = (const float*)d_in[0];
  const float* weight = (const float*)d_in[1];
  const float* bias   = (const float*)d_in[2];
  const int* seg      = (const int*)d_in[3];
  const int* sbatch   = (const int*)d_in[4];
  const int* spos     = (const int*)d_in[5];
  float* out = (float*)d_out;

  unsigned short* wsB = (unsigned short*)d_ws;                    // 64 KB bf16 weight
  int* starts = (int*)((char*)d_ws + DOUT * DIN * sizeof(unsigned short));  // 8 KB

  prep_kernel<<<512, 256, 0, stream>>>(weight, seg, wsB, starts);
  pool_kernel<<<S_SENT, 256, 0, stream>>>(tokens, bias, wsB, starts, sbatch, spos, out);
}

// Round 10
// 153.844 us; speedup vs baseline: 2.3450x; 1.0161x over previous
//
#include <hip/hip_runtime.h>
#include <hip/hip_bf16.h>

#define T_WORDS 800000
#define S_SENT 2048
#define DIN 256
#define DOUT 128
#define CHUNK 32

typedef short bf16x8 __attribute__((ext_vector_type(8)));
typedef float f32x4 __attribute__((ext_vector_type(4)));

__device__ __forceinline__ unsigned short f2bf(float f) {
  unsigned int u = __builtin_bit_cast(unsigned int, f);
  u += 0x7fffu + ((u >> 16) & 1u);   // round-to-nearest-even
  return (unsigned short)(u >> 16);
}

// Prep: weight f32 -> bf16 into ws; sentence start offsets from sorted seg_ids.
__global__ void prep_kernel(const float* __restrict__ weight,
                            const int* __restrict__ seg,
                            unsigned short* __restrict__ wsB,
                            int* __restrict__ starts) {
  int tid = blockIdx.x * blockDim.x + threadIdx.x;
  int stride = gridDim.x * blockDim.x;
  for (int j = tid; j < DOUT * DIN; j += stride)
    wsB[j] = f2bf(weight[j]);
  for (int j = tid; j < T_WORDS; j += stride) {
    if (j == 0) {
      starts[seg[0]] = 0;
    } else {
      int s1 = seg[j], s0 = seg[j - 1];
      if (s1 != s0) starts[s1] = j;
    }
  }
}

// One block per sentence. 4 waves; wave w owns output cols [32w, 32w+32).
// 32-row chunks, double-buffered LDS, T14 async-STAGE split:
//   issue loads(c+1) -> compute(c) -> cvt+write(c+1) -> barrier.
__global__ __launch_bounds__(256) void pool_kernel(
    const float* __restrict__ tokens,
    const float* __restrict__ bias,
    const unsigned short* __restrict__ wsB,
    const int* __restrict__ starts,
    const int* __restrict__ sent_batch,
    const int* __restrict__ sent_pos,
    float* __restrict__ out) {
  __shared__ alignas(16) unsigned short Alds[2][CHUNK * DIN];  // 2 x 16 KB

  const int s = blockIdx.x;
  const int start = starts[s];
  const int end = (s == S_SENT - 1) ? T_WORDS : starts[s + 1];
  const int lane = (int)(threadIdx.x & 63);
  const int wv = (int)(threadIdx.x >> 6);

  // B fragments in registers: lane holds col = 16n + (lane&15), k = 8*(lane>>4)+j.
  bf16x8 bfrag[2][8];
#pragma unroll
  for (int n = 0; n < 2; ++n) {
    const int col = 32 * wv + 16 * n + (lane & 15);
    const unsigned short* wrow = wsB + col * DIN + 8 * (lane >> 4);
#pragma unroll
    for (int kk = 0; kk < 8; ++kk)
      bfrag[n][kk] = *(const bf16x8*)(wrow + 32 * kk);
  }

  // Staging decomposition: thread t, iter it covers row = (t>>5) + 8*it,
  // cols [8*(t&31), 8*(t&31)+8) -> 2 float4 loads (32B contiguous per thread).
  const int srow0 = (int)(threadIdx.x >> 5);
  const int sk8 = (int)(threadIdx.x & 31);

  float runmax0 = -INFINITY, runmax1 = -INFINITY;
  float4 pf[4][2];

#define ISSUE_LOADS(WBASE)                                                    \
  {                                                                           \
    _Pragma("unroll") for (int it = 0; it < 4; ++it) {                        \
      int word = (WBASE) + srow0 + 8 * it;                                    \
      if (word < end) {                                                       \
        const float4* src =                                                   \
            (const float4*)(tokens + (size_t)word * DIN + sk8 * 8);           \
        pf[it][0] = src[0];                                                   \
        pf[it][1] = src[1];                                                   \
      }                                                                       \
    }                                                                         \
  }

#define WRITE_STAGE(BUF)                                                      \
  {                                                                           \
    _Pragma("unroll") for (int it = 0; it < 4; ++it) {                        \
      int row = srow0 + 8 * it;                                               \
      float4 f0 = pf[it][0], f1 = pf[it][1];                                  \
      bf16x8 v;                                                               \
      v[0] = (short)f2bf(f0.x); v[1] = (short)f2bf(f0.y);                     \
      v[2] = (short)f2bf(f0.z); v[3] = (short)f2bf(f0.w);                     \
      v[4] = (short)f2bf(f1.x); v[5] = (short)f2bf(f1.y);                     \
      v[6] = (short)f2bf(f1.z); v[7] = (short)f2bf(f1.w);                     \
      int idx = (row * DIN + sk8 * 8) ^ ((row & 7) << 3);                     \
      *(bf16x8*)&Alds[BUF][idx] = v;                                          \
    }                                                                         \
  }

#define COMPUTE(BUF, WBASE)                                                   \
  {                                                                           \
    _Pragma("unroll") for (int m = 0; m < 2; ++m) {                           \
      f32x4 acc0 = (f32x4){0.f, 0.f, 0.f, 0.f};                               \
      f32x4 acc1 = (f32x4){0.f, 0.f, 0.f, 0.f};                               \
      const int arow = 16 * m + (lane & 15);                                  \
      const int abase = arow * DIN + 8 * (lane >> 4);                         \
      const int axor = (lane & 7) << 3;                                       \
      _Pragma("unroll") for (int kk = 0; kk < 8; ++kk) {                      \
        bf16x8 a = *(const bf16x8*)&Alds[BUF][(abase + 32 * kk) ^ axor];      \
        acc0 = __builtin_amdgcn_mfma_f32_16x16x32_bf16(a, bfrag[0][kk], acc0, \
                                                       0, 0, 0);              \
        acc1 = __builtin_amdgcn_mfma_f32_16x16x32_bf16(a, bfrag[1][kk], acc1, \
                                                       0, 0, 0);              \
      }                                                                       \
      const int w0 = (WBASE) + 16 * m + 4 * (lane >> 4);                      \
      _Pragma("unroll") for (int r = 0; r < 4; ++r) {                         \
        if (w0 + r < end) {                                                   \
          runmax0 = fmaxf(runmax0, acc0[r]);                                  \
          runmax1 = fmaxf(runmax1, acc1[r]);                                  \
        }                                                                     \
      }                                                                       \
    }                                                                         \
  }

  const int nch = (end - start + CHUNK - 1) / CHUNK;

  // Prologue: stage chunk 0 into buffer 0.
  ISSUE_LOADS(start)
  WRITE_STAGE(0)
  __syncthreads();

  for (int c = 0; c < nch; ++c) {
    const int cur = c & 1;
    const int wbase = start + c * CHUNK;
    if (c + 1 < nch) ISSUE_LOADS(wbase + CHUNK)   // loads in flight during MFMA
    COMPUTE(cur, wbase)
    if (c + 1 < nch) WRITE_STAGE(cur ^ 1)
    __syncthreads();
  }

  // Reduce across the 4 row-groups (lanes differing in bits 4,5).
  runmax0 = fmaxf(runmax0, __shfl_xor(runmax0, 16, 64));
  runmax0 = fmaxf(runmax0, __shfl_xor(runmax0, 32, 64));
  runmax1 = fmaxf(runmax1, __shfl_xor(runmax1, 16, 64));
  runmax1 = fmaxf(runmax1, __shfl_xor(runmax1, 32, 64));

  if (lane < 16) {
    const int sb = sent_batch[s], sp = sent_pos[s];
    float* o = out + ((size_t)sb * 64 + sp) * DOUT;
    const int c0 = 32 * wv + lane;
    o[c0] = runmax0 + bias[c0];
    o[c0 + 16] = runmax1 + bias[c0 + 16];
  }
}

extern "C" void kernel_launch(void* const* d_in, const int* in_sizes, int n_in,
                              void* d_out, int out_size, void* d_ws, size_t ws_size,
                              hipStream_t stream) {
  const float* tokens = (const float*)d_in[0];
  const float* weight = (const float*)d_in[1];
  const float* bias   = (const float*)d_in[2];
  const int* seg      = (const int*)d_in[3];
  const int* sbatch   = (const int*)d_in[4];
  const int* spos     = (const int*)d_in[5];
  float* out = (float*)d_out;

  unsigned short* wsB = (unsigned short*)d_ws;                    // 64 KB bf16 weight
  int* starts = (int*)((char*)d_ws + DOUT * DIN * sizeof(unsigned short));  // 8 KB

  prep_kernel<<<512, 256, 0, stream>>>(weight, seg, wsB, starts);
  pool_kernel<<<S_SENT, 256, 0, stream>>>(tokens, bias, wsB, starts, sbatch, spos, out);
}